// Round 2
// baseline (141.873 us; speedup 1.0000x reference)
//
#include <hip/hip_runtime.h>
#include <math.h>

// OneClassLoss: BS=128, HW=128. x1,x2: (128,1,128,128) fp32. Output: scalar fp32.
//
// ws layout (floats):
//   [0,128)        na[i]   = ||a_i||^2
//   [128,256)      nb[j]   = ||b_j||^2
//   [256,16640)    G[i*128+j] = a_i . b_j
//   [16640,24960)  S[v*128+u] = sum over 256 images of |FFT2|^2 at (u,v), v in [0,64]
//                  (u permuted consistently across images; weight 2 for v in [1,63])
//   [33024,33152)  rowvals[i] = LSE_i - Dist[i,i]

#define WS_NA    0
#define WS_NB    128
#define WS_G     256
#define WS_S     16640
#define WS_ROW   33024

#define PI_F 3.14159265358979323846f

// ---------------- Kernel 1: row norms + zero the PSD accumulator ----------------
__global__ __launch_bounds__(256) void ocl_norms_zero(const float* __restrict__ x1,
                                                      const float* __restrict__ x2,
                                                      float* __restrict__ ws) {
    int b = blockIdx.x, t = threadIdx.x;
    float* S = ws + WS_S;
    if (t < 64) S[b * 64 + t] = 0.0f;   // 256*64 = 16384 >= 8320 used

    const float* src = (b < 128) ? (x1 + (size_t)b * 16384)
                                 : (x2 + (size_t)(b - 128) * 16384);
    const float4* s4 = (const float4*)src;
    float acc = 0.0f;
    #pragma unroll
    for (int s = 0; s < 16; ++s) {
        float4 v = s4[t + 256 * s];
        acc += v.x * v.x + v.y * v.y + v.z * v.z + v.w * v.w;
    }
    for (int off = 32; off >= 1; off >>= 1) acc += __shfl_down(acc, off);
    __shared__ float wsum[4];
    if ((t & 63) == 0) wsum[t >> 6] = acc;
    __syncthreads();
    if (t == 0) {
        float tot = wsum[0] + wsum[1] + wsum[2] + wsum[3];
        if (b < 128) ws[WS_NA + b] = tot;
        else         ws[WS_NB + (b - 128)] = tot;
    }
}

// ---------------- Kernel 2: Gram matrix G = A B^T ----------------
__global__ __launch_bounds__(256) void ocl_gram(const float* __restrict__ x1,
                                                const float* __restrict__ x2,
                                                float* __restrict__ ws) {
    int i0 = (blockIdx.x >> 4) * 8;
    int j0 = (blockIdx.x & 15) * 8;
    int t = threadIdx.x;
    const float4* A = (const float4*)x1;
    const float4* B = (const float4*)x2;
    float acc[8][8];
    #pragma unroll
    for (int r = 0; r < 8; ++r)
        #pragma unroll
        for (int c = 0; c < 8; ++c) acc[r][c] = 0.0f;

    for (int s = 0; s < 16; ++s) {
        int q = t + 256 * s;
        float4 av[8], bv[8];
        #pragma unroll
        for (int r = 0; r < 8; ++r) av[r] = A[(size_t)(i0 + r) * 4096 + q];
        #pragma unroll
        for (int c = 0; c < 8; ++c) bv[c] = B[(size_t)(j0 + c) * 4096 + q];
        #pragma unroll
        for (int r = 0; r < 8; ++r)
            #pragma unroll
            for (int c = 0; c < 8; ++c)
                acc[r][c] += av[r].x * bv[c].x + av[r].y * bv[c].y +
                             av[r].z * bv[c].z + av[r].w * bv[c].w;
    }

    __shared__ float red[4][64];
    float* G = ws + WS_G;
    #pragma unroll
    for (int r = 0; r < 8; ++r) {
        #pragma unroll
        for (int c = 0; c < 8; ++c) {
            float v = acc[r][c];
            for (int off = 32; off >= 1; off >>= 1) v += __shfl_down(v, off);
            if ((t & 63) == 0) red[t >> 6][r * 8 + c] = v;
        }
    }
    __syncthreads();
    if (t < 64) {
        float v = red[0][t] + red[1][t] + red[2][t] + red[3][t];
        G[(size_t)(i0 + (t >> 3)) * 128 + (j0 + (t & 7))] = v;
    }
}

// ---------------- Register/shuffle 128-pt complex FFT (DIF, bit-reversed out) --
// Lane l holds points y[l] (slot0) and y[l+64] (slot1). Output order is a fixed
// permutation (2*br6(l)+s at position s*64+l) — consistent across images, so
// PSD bin identity is preserved without bit-reversal.
__device__ __forceinline__ void fft128_reg(float& s0r, float& s0i,
                                           float& s1r, float& s1i,
                                           float cA, float sA,
                                           const float* wr, const float* wi,
                                           int lane) {
    // Stage A: distance 64; even problem e = y[l]+y[l+64], odd o = (y[l]-y[l+64])*W_128^l
    float er = s0r + s1r, ei = s0i + s1i;
    float dr = s0r - s1r, di = s0i - s1i;
    float orr = dr * cA - di * sA;
    float oii = dr * sA + di * cA;
    // Six cross-lane DIF stages (64-pt FFT per slot), m = 32..1
    #pragma unroll
    for (int st = 0; st < 6; ++st) {
        int m = 32 >> st;
        bool up = (lane & m) == 0;
        float tr = __shfl_xor(er, m), ti = __shfl_xor(ei, m);
        float ar = tr - er, ai = ti - ei;
        float e2r = up ? (er + tr) : (ar * wr[st] - ai * wi[st]);
        float e2i = up ? (ei + ti) : (ar * wi[st] + ai * wr[st]);
        tr = __shfl_xor(orr, m); ti = __shfl_xor(oii, m);
        float br_ = tr - orr, bi_ = ti - oii;
        float o2r = up ? (orr + tr) : (br_ * wr[st] - bi_ * wi[st]);
        float o2i = up ? (oii + ti) : (br_ * wi[st] + bi_ * wr[st]);
        er = e2r; ei = e2i; orr = o2r; oii = o2i;
    }
    s0r = er; s0i = ei; s1r = orr; s1i = oii;
}

// ---------------- Kernel 3: per-image real 2D FFT + PSD accumulate ----------------
// Row pairs packed as complex (halves row FFT count); Z[64][128] complex in LDS
// (exactly 64 KB); column spectra rebuilt on the fly via Hermitian unpack;
// columns v in [0,64] only (weight 2 for v in [1,63] applied in ocl_final).
// LDS layout swizzle: Z_p[f] stored at column (f+p)&127 -> column-phase reads
// hit all 32 banks (conflict-free), row-phase writes are 2-way (free).
__global__ __launch_bounds__(256) void ocl_fft_psd(const float* __restrict__ x1,
                                                   const float* __restrict__ x2,
                                                   float* __restrict__ ws) {
    __shared__ float zre[64 * 128];
    __shared__ float zim[64 * 128];
    int t = threadIdx.x, lane = t & 63, wave = t >> 6;
    int img = blockIdx.x;
    float* S = ws + WS_S;
    const float* src = (img < 128) ? (x1 + (size_t)img * 16384)
                                   : (x2 + (size_t)(img - 128) * 16384);

    // Per-lane twiddles: stage A = W_128^l; stage st (m=32>>st): W_{2m}^{l&(m-1)}
    float cA, sA, wr[6], wi[6];
    {
        float th = -PI_F * (float)lane / 64.0f;
        sincosf(th, &sA, &cA);
        #pragma unroll
        for (int st = 0; st < 6; ++st) {
            int m = 32 >> st;
            float a = -PI_F * (float)(lane & (m - 1)) / (float)m;
            sincosf(a, &wi[st], &wr[st]);
        }
    }
    int rb = (int)(__brev((unsigned)lane) >> 26);  // br6(lane)

    // ---- Row phase: 64 packed row-pair FFTs, 16 per wave ----
    for (int p = wave * 16; p < wave * 16 + 16; ++p) {
        const float* r0 = src + p * 256 + lane;
        float s0r = r0[0],   s1r = r0[64];
        float s0i = r0[128], s1i = r0[192];
        fft128_reg(s0r, s0i, s1r, s1i, cA, sA, wr, wi, lane);
        int f0 = (2 * rb + p) & 127;        // swizzled column for freq 2*br6(l)
        int f1 = (2 * rb + 1 + p) & 127;    // freq 2*br6(l)+1
        zre[p * 128 + f0] = s0r; zim[p * 128 + f0] = s0i;
        zre[p * 128 + f1] = s1r; zim[p * 128 + f1] = s1i;
    }
    __syncthreads();

    // ---- Column phase: 65 column FFTs (k=0..64), round-robin over waves ----
    int p0 = (lane >> 1), p1 = 32 + (lane >> 1);
    int par = lane & 1;
    for (int k = wave; k < 65; k += 4) {
        float v0r, v0i, v1r, v1i;
        if (k == 0 || k == 64) {
            // R[2p][k] = Re(Z_p[k]), R[2p+1][k] = Im(Z_p[k]) (real columns)
            int c0 = (k + p0) & 127, c1 = (k + p1) & 127;
            float Z0r = zre[p0 * 128 + c0], Z0i = zim[p0 * 128 + c0];
            float Z1r = zre[p1 * 128 + c1], Z1i = zim[p1 * 128 + c1];
            v0r = par ? Z0i : Z0r; v0i = 0.0f;
            v1r = par ? Z1i : Z1r; v1i = 0.0f;
        } else {
            int kn = 128 - k;
            // slot0 (r = lane, p = p0)
            int ck = (k + p0) & 127, cn = (kn + p0) & 127;
            float Zkr = zre[p0 * 128 + ck], Zki = zim[p0 * 128 + ck];
            float Znr = zre[p0 * 128 + cn], Zni = zim[p0 * 128 + cn];
            float e0r = 0.5f * (Zkr + Znr), e0i = 0.5f * (Zki - Zni); // even row
            float q0r = 0.5f * (Zki + Zni), q0i = 0.5f * (Znr - Zkr); // odd row
            v0r = par ? q0r : e0r; v0i = par ? q0i : e0i;
            // slot1 (r = lane+64, p = p1)
            ck = (k + p1) & 127; cn = (kn + p1) & 127;
            Zkr = zre[p1 * 128 + ck]; Zki = zim[p1 * 128 + ck];
            Znr = zre[p1 * 128 + cn]; Zni = zim[p1 * 128 + cn];
            float e1r = 0.5f * (Zkr + Znr), e1i = 0.5f * (Zki - Zni);
            float q1r = 0.5f * (Zki + Zni), q1i = 0.5f * (Znr - Zkr);
            v1r = par ? q1r : e1r; v1i = par ? q1i : e1i;
        }
        fft128_reg(v0r, v0i, v1r, v1i, cA, sA, wr, wi, lane);
        atomicAdd(&S[k * 128 + lane],      v0r * v0r + v0i * v0i);
        atomicAdd(&S[k * 128 + 64 + lane], v1r * v1r + v1i * v1i);
    }
}

// ---------------- Kernel 4: per-row logsumexp of Dist ----------------
__global__ __launch_bounds__(128) void ocl_lse(float* __restrict__ ws) {
    int i = blockIdx.x, j = threadIdx.x;
    const float* na = ws + WS_NA;
    const float* nb = ws + WS_NB;
    const float* G  = ws + WS_G;
    float* rowvals  = ws + WS_ROW;
    float d = sqrtf(fmaxf(na[i] + nb[j] - 2.0f * G[(size_t)i * 128 + j], 0.0f));
    __shared__ float sh[2], sh2[2], dii;
    if (j == i) dii = d;
    float mx = d;
    for (int off = 32; off >= 1; off >>= 1) mx = fmaxf(mx, __shfl_down(mx, off));
    if ((j & 63) == 0) sh[j >> 6] = mx;
    __syncthreads();
    float rowmax = fmaxf(sh[0], sh[1]);
    float sm = expf(d - rowmax);
    for (int off = 32; off >= 1; off >>= 1) sm += __shfl_down(sm, off);
    if ((j & 63) == 0) sh2[j >> 6] = sm;
    __syncthreads();
    if (j == 0) rowvals[i] = rowmax + logf(sh2[0] + sh2[1]) - dii;
}

// ---------------- Kernel 5: final reduction -> scalar ----------------
// r = mean(log avgpsd) - log(mean avgpsd); the 1/256 on S cancels.
// Bin weights: v=0 and v=64 count once, v in [1,63] count twice (Hermitian mirror).
__global__ __launch_bounds__(256) void ocl_final(float* __restrict__ ws,
                                                 float* __restrict__ out) {
    int t = threadIdx.x;
    const float* S = ws + WS_S;
    const float* rowvals = ws + WS_ROW;
    float sumS = 0.0f, sumLog = 0.0f;
    for (int e = 0; e < 33; ++e) {
        int idx = t + 256 * e;
        if (idx < 8320) {
            float v = S[idx];
            int kcol = idx >> 7;
            float w = (kcol == 0 || kcol == 64) ? 1.0f : 2.0f;
            sumS += w * v;
            sumLog += w * logf(v);
        }
    }
    float rv = (t < 128) ? rowvals[t] : 0.0f;
    __shared__ float a1[4], a2[4], a3[4];
    for (int off = 32; off >= 1; off >>= 1) {
        sumS   += __shfl_down(sumS, off);
        sumLog += __shfl_down(sumLog, off);
        rv     += __shfl_down(rv, off);
    }
    if ((t & 63) == 0) { a1[t >> 6] = sumS; a2[t >> 6] = sumLog; a3[t >> 6] = rv; }
    __syncthreads();
    if (t == 0) {
        float S_ = a1[0] + a1[1] + a1[2] + a1[3];
        float L_ = a2[0] + a2[1] + a2[2] + a2[3];
        float R_ = a3[0] + a3[1] + a3[2] + a3[3];
        float ce = R_ / 128.0f;
        float r  = L_ / 16384.0f - logf(S_ / 16384.0f);
        out[0] = ce - 0.1f * r;
    }
}

extern "C" void kernel_launch(void* const* d_in, const int* in_sizes, int n_in,
                              void* d_out, int out_size, void* d_ws, size_t ws_size,
                              hipStream_t stream) {
    (void)in_sizes; (void)n_in; (void)out_size; (void)ws_size;
    const float* x1 = (const float*)d_in[0];
    const float* x2 = (const float*)d_in[1];
    float* ws  = (float*)d_ws;
    float* out = (float*)d_out;

    hipLaunchKernelGGL(ocl_norms_zero, dim3(256), dim3(256), 0, stream, x1, x2, ws);
    hipLaunchKernelGGL(ocl_gram,       dim3(256), dim3(256), 0, stream, x1, x2, ws);
    hipLaunchKernelGGL(ocl_fft_psd,    dim3(256), dim3(256), 0, stream, x1, x2, ws);
    hipLaunchKernelGGL(ocl_lse,        dim3(128), dim3(128), 0, stream, ws);
    hipLaunchKernelGGL(ocl_final,      dim3(1),   dim3(256), 0, stream, ws, out);
}

// Round 3
// 129.839 us; speedup vs baseline: 1.0927x; 1.0927x over previous
//
#include <hip/hip_runtime.h>
#include <math.h>

// OneClassLoss: BS=128, HW=128. x1,x2: (128,1,128,128) fp32. Output: scalar fp32.
//
// ws layout (floats):
//   [0,128)          na[i] = ||a_i||^2        (atomicAdd from fft kernel)
//   [128,256)        nb[j] = ||b_j||^2
//   [256,65792)      Gp[ks][i*128+j], ks in [0,4): K-split partial Gram
//   [65792,74112)    S[v*128+u] = sum over 256 images of |FFT2|^2, v in [0,64]
// All zeroed by one hipMemsetAsync (296448 bytes) at the head of the graph.

#define WS_NA    0
#define WS_NB    128
#define WS_GP    256
#define WS_S     65792
#define WS_END   74112

#define PI_F 3.14159265358979323846f

// ---------------- Kernel 1: partial Gram G = A B^T, 16x16 tile x 4-way K-split --
// 256 blocks x 256 threads. Each wave owns one 8x8 quadrant of the 16x16 tile;
// waves sharing A-rows / B-cols hit L1. Total L2/L3 traffic: 128 MB (vs 256 MB
// for 8x8 tiles).
__global__ __launch_bounds__(256) void ocl_gram(const float* __restrict__ A_,
                                                const float* __restrict__ B_,
                                                float* __restrict__ ws) {
    int tile = blockIdx.x & 63;      // 8x8 grid of 16x16 tiles
    int ks   = blockIdx.x >> 6;      // 4 K-splits
    int t = threadIdx.x, lane = t & 63, wave = t >> 6;
    int iw = (tile >> 3) * 16 + (wave >> 1) * 8;
    int jw = (tile & 7)  * 16 + (wave & 1)  * 8;
    const float4* A = (const float4*)A_;
    const float4* B = (const float4*)B_;
    int qbase = ks * 1024;           // 1024 quads = 4096 floats per split

    float acc[8][8];
    #pragma unroll
    for (int r = 0; r < 8; ++r)
        #pragma unroll
        for (int c = 0; c < 8; ++c) acc[r][c] = 0.0f;

    for (int s = 0; s < 16; ++s) {
        int q = qbase + lane + 64 * s;
        float4 av[8], bv[8];
        #pragma unroll
        for (int r = 0; r < 8; ++r) av[r] = A[(size_t)(iw + r) * 4096 + q];
        #pragma unroll
        for (int c = 0; c < 8; ++c) bv[c] = B[(size_t)(jw + c) * 4096 + q];
        #pragma unroll
        for (int r = 0; r < 8; ++r)
            #pragma unroll
            for (int c = 0; c < 8; ++c)
                acc[r][c] += av[r].x * bv[c].x + av[r].y * bv[c].y +
                             av[r].z * bv[c].z + av[r].w * bv[c].w;
    }

    // Butterfly-reduce each (r,c); lane rc keeps sum for (rc>>3, rc&7).
    float out = 0.0f;
    #pragma unroll
    for (int rc = 0; rc < 64; ++rc) {
        float v = acc[rc >> 3][rc & 7];
        for (int off = 32; off >= 1; off >>= 1) v += __shfl_xor(v, off);
        if (lane == rc) out = v;
    }
    float* Gp = ws + WS_GP + ks * 16384;
    Gp[(size_t)(iw + (lane >> 3)) * 128 + jw + (lane & 7)] = out;
}

// ---------------- Register/shuffle 128-pt complex FFT (DIF, bit-reversed out) --
__device__ __forceinline__ void fft128_reg(float& s0r, float& s0i,
                                           float& s1r, float& s1i,
                                           float cA, float sA,
                                           const float* wr, const float* wi,
                                           int lane) {
    float er = s0r + s1r, ei = s0i + s1i;
    float dr = s0r - s1r, di = s0i - s1i;
    float orr = dr * cA - di * sA;
    float oii = dr * sA + di * cA;
    #pragma unroll
    for (int st = 0; st < 6; ++st) {
        int m = 32 >> st;
        bool up = (lane & m) == 0;
        float tr = __shfl_xor(er, m), ti = __shfl_xor(ei, m);
        float ar = tr - er, ai = ti - ei;
        float e2r = up ? (er + tr) : (ar * wr[st] - ai * wi[st]);
        float e2i = up ? (ei + ti) : (ar * wi[st] + ai * wr[st]);
        tr = __shfl_xor(orr, m); ti = __shfl_xor(oii, m);
        float br_ = tr - orr, bi_ = ti - oii;
        float o2r = up ? (orr + tr) : (br_ * wr[st] - bi_ * wi[st]);
        float o2i = up ? (oii + ti) : (br_ * wi[st] + bi_ * wr[st]);
        er = e2r; ei = e2i; orr = o2r; oii = o2i;
    }
    s0r = er; s0i = ei; s1r = orr; s1i = oii;
}

// ---------------- Kernel 2: per-image real 2D FFT + PSD + fused norms ----------
// 1024 threads (16 waves -> 4 waves/SIMD for latency hiding; was 1/SIMD).
// Row pairs packed complex; Z[64][128] in LDS = exactly 64 KB; Hermitian unpack
// on the fly; columns v in [0,64] (mirror weight 2 applied in tail).
__global__ __launch_bounds__(1024) void ocl_fft_psd(const float* __restrict__ x1,
                                                    const float* __restrict__ x2,
                                                    float* __restrict__ ws) {
    __shared__ float zre[64 * 128];
    __shared__ float zim[64 * 128];
    int t = threadIdx.x, lane = t & 63, wave = t >> 6;
    int img = blockIdx.x;
    float* S = ws + WS_S;
    const float* src = (img < 128) ? (x1 + (size_t)img * 16384)
                                   : (x2 + (size_t)(img - 128) * 16384);

    float cA, sA, wr[6], wi[6];
    {
        float th = -PI_F * (float)lane / 64.0f;
        sincosf(th, &sA, &cA);
        #pragma unroll
        for (int st = 0; st < 6; ++st) {
            int m = 32 >> st;
            float a = -PI_F * (float)(lane & (m - 1)) / (float)m;
            sincosf(a, &wi[st], &wr[st]);
        }
    }
    int rb = (int)(__brev((unsigned)lane) >> 26);  // br6(lane)

    // ---- Row phase: 64 packed row-pair FFTs, 4 per wave; fused ||x||^2 ----
    float nrm = 0.0f;
    #pragma unroll
    for (int pi = 0; pi < 4; ++pi) {
        int p = wave * 4 + pi;
        const float* r0 = src + p * 256 + lane;
        float s0r = r0[0],   s1r = r0[64];
        float s0i = r0[128], s1i = r0[192];
        nrm += s0r * s0r + s1r * s1r + s0i * s0i + s1i * s1i;
        fft128_reg(s0r, s0i, s1r, s1i, cA, sA, wr, wi, lane);
        int f0 = (2 * rb + p) & 127;
        int f1 = (2 * rb + 1 + p) & 127;
        zre[p * 128 + f0] = s0r; zim[p * 128 + f0] = s0i;
        zre[p * 128 + f1] = s1r; zim[p * 128 + f1] = s1i;
    }
    for (int off = 32; off >= 1; off >>= 1) nrm += __shfl_xor(nrm, off);
    if (lane == 0) atomicAdd(&ws[img], nrm);   // na[img] / nb[img-128] contiguous
    __syncthreads();

    // ---- Column phase: 65 column FFTs (k=0..64) over 16 waves ----
    int p0 = (lane >> 1), p1 = 32 + (lane >> 1);
    int par = lane & 1;
    for (int k = wave; k < 65; k += 16) {
        float v0r, v0i, v1r, v1i;
        if (k == 0 || k == 64) {
            int c0 = (k + p0) & 127, c1 = (k + p1) & 127;
            float Z0r = zre[p0 * 128 + c0], Z0i = zim[p0 * 128 + c0];
            float Z1r = zre[p1 * 128 + c1], Z1i = zim[p1 * 128 + c1];
            v0r = par ? Z0i : Z0r; v0i = 0.0f;
            v1r = par ? Z1i : Z1r; v1i = 0.0f;
        } else {
            int kn = 128 - k;
            int ck = (k + p0) & 127, cn = (kn + p0) & 127;
            float Zkr = zre[p0 * 128 + ck], Zki = zim[p0 * 128 + ck];
            float Znr = zre[p0 * 128 + cn], Zni = zim[p0 * 128 + cn];
            float e0r = 0.5f * (Zkr + Znr), e0i = 0.5f * (Zki - Zni);
            float q0r = 0.5f * (Zki + Zni), q0i = 0.5f * (Znr - Zkr);
            v0r = par ? q0r : e0r; v0i = par ? q0i : e0i;
            ck = (k + p1) & 127; cn = (kn + p1) & 127;
            Zkr = zre[p1 * 128 + ck]; Zki = zim[p1 * 128 + ck];
            Znr = zre[p1 * 128 + cn]; Zni = zim[p1 * 128 + cn];
            float e1r = 0.5f * (Zkr + Znr), e1i = 0.5f * (Zki - Zni);
            float q1r = 0.5f * (Zki + Zni), q1i = 0.5f * (Znr - Zkr);
            v1r = par ? q1r : e1r; v1i = par ? q1i : e1i;
        }
        fft128_reg(v0r, v0i, v1r, v1i, cA, sA, wr, wi, lane);
        atomicAdd(&S[k * 128 + lane],      v0r * v0r + v0i * v0i);
        atomicAdd(&S[k * 128 + 64 + lane], v1r * v1r + v1i * v1i);
    }
}

// ---------------- Kernel 3: tail — LSE rows + PSD reduction -> scalar ----------
// 1 block x 1024 threads. Wave w handles rows w*8..w*8+7 (lane -> cols j, j+64).
__global__ __launch_bounds__(1024) void ocl_tail(const float* __restrict__ ws,
                                                 float* __restrict__ out) {
    int t = threadIdx.x, lane = t & 63, wave = t >> 6;
    const float* na = ws + WS_NA;
    const float* nb = ws + WS_NB;
    const float* Gp = ws + WS_GP;
    const float* S  = ws + WS_S;

    float rowacc = 0.0f;
    #pragma unroll
    for (int ri = 0; ri < 8; ++ri) {
        int i = wave * 8 + ri;
        int j0 = lane, j1 = 64 + lane;
        size_t b = (size_t)i * 128;
        float g0 = Gp[b + j0] + Gp[16384 + b + j0] + Gp[32768 + b + j0] + Gp[49152 + b + j0];
        float g1 = Gp[b + j1] + Gp[16384 + b + j1] + Gp[32768 + b + j1] + Gp[49152 + b + j1];
        float d0 = sqrtf(fmaxf(na[i] + nb[j0] - 2.0f * g0, 0.0f));
        float d1 = sqrtf(fmaxf(na[i] + nb[j1] - 2.0f * g1, 0.0f));
        float mx = fmaxf(d0, d1);
        for (int off = 32; off >= 1; off >>= 1) mx = fmaxf(mx, __shfl_xor(mx, off));
        float sm = expf(d0 - mx) + expf(d1 - mx);
        for (int off = 32; off >= 1; off >>= 1) sm += __shfl_xor(sm, off);
        float dii = (i < 64) ? __shfl(d0, i) : __shfl(d1, i - 64);
        rowacc += mx + logf(sm) - dii;   // identical on all lanes
    }

    float sumS = 0.0f, sumLog = 0.0f;
    #pragma unroll
    for (int e = 0; e < 9; ++e) {
        int idx = t + 1024 * e;
        if (idx < 8320) {
            float v = S[idx];
            int kcol = idx >> 7;
            float w = (kcol == 0 || kcol == 64) ? 1.0f : 2.0f;
            sumS += w * v;
            sumLog += w * logf(v);
        }
    }
    for (int off = 32; off >= 1; off >>= 1) {
        sumS   += __shfl_xor(sumS, off);
        sumLog += __shfl_xor(sumLog, off);
    }
    __shared__ float aS[16], aL[16], aR[16];
    if (lane == 0) { aS[wave] = sumS; aL[wave] = sumLog; aR[wave] = rowacc; }
    __syncthreads();
    if (t == 0) {
        float S_ = 0.0f, L_ = 0.0f, R_ = 0.0f;
        #pragma unroll
        for (int w = 0; w < 16; ++w) { S_ += aS[w]; L_ += aL[w]; R_ += aR[w]; }
        float ce = R_ / 128.0f;
        float r  = L_ / 16384.0f - logf(S_ / 16384.0f);
        out[0] = ce - 0.1f * r;
    }
}

extern "C" void kernel_launch(void* const* d_in, const int* in_sizes, int n_in,
                              void* d_out, int out_size, void* d_ws, size_t ws_size,
                              hipStream_t stream) {
    (void)in_sizes; (void)n_in; (void)out_size; (void)ws_size;
    const float* x1 = (const float*)d_in[0];
    const float* x2 = (const float*)d_in[1];
    float* ws  = (float*)d_ws;
    float* out = (float*)d_out;

    hipMemsetAsync(ws, 0, WS_END * sizeof(float), stream);
    hipLaunchKernelGGL(ocl_gram,    dim3(256), dim3(256),  0, stream, x1, x2, ws);
    hipLaunchKernelGGL(ocl_fft_psd, dim3(256), dim3(1024), 0, stream, x1, x2, ws);
    hipLaunchKernelGGL(ocl_tail,    dim3(1),   dim3(1024), 0, stream, ws, out);
}

// Round 4
// 121.102 us; speedup vs baseline: 1.1715x; 1.0721x over previous
//
#include <hip/hip_runtime.h>
#include <math.h>

// OneClassLoss: BS=128, HW=128. x1,x2: (128,1,128,128) fp32. Output: scalar fp32.
//
// ws layout (floats) — every region fully overwritten each launch (no memset):
//   [0,256)              na[0..128)|nb[0..128)   (written by ocl_reduce norm branch)
//   [256,16640)          G[i*128+j] final Gram   (written by ocl_reduce gram branch)
//   [16640,20736)        NP[img*16+wave] norm partials (ocl_fft_psd)
//   [20736,4215040)      Gp[ks][16384] partial Gram slabs (ocl_gram)
//   [4215040,6344960)    P[img][8320] per-image PSD (ocl_fft_psd)
//   [6344960,6345025)    PS[k] = w_k * sum_u S[k,u]          (ocl_reduce)
//   [6345025,6345090)    PL[k] = w_k * sum_u log S[k,u]      (ocl_reduce)

#define WS_N     0
#define WS_G     256
#define WS_NP    16640
#define WS_GP    20736
#define WS_P     4215040
#define WS_PS    6344960
#define WS_PL    6345025

#define PI_F 3.14159265358979323846f

// ---------------- Kernel 1: Gram partials, LDS-staged GEMM, 256 K-splits -------
// Block ks covers K-chunk [ks*64, ks*64+64) for the whole 128x128 output.
// LDS: A-tile + B-tile, 128 rows x 16 quads each, XOR-swizzled (qk ^ (row>>3)&7)
// -> staging b128 writes conflict-free, A-frag reads broadcast, B-frag 2-way.
__global__ __launch_bounds__(256) void ocl_gram(const float* __restrict__ A_,
                                                const float* __restrict__ B_,
                                                float* __restrict__ ws) {
    __shared__ float4 As[128 * 16];
    __shared__ float4 Bs[128 * 16];
    int ks = blockIdx.x;
    int k0q = ks * 16;                 // quad offset of this K-chunk
    int t = threadIdx.x;
    const float4* A = (const float4*)A_;
    const float4* B = (const float4*)B_;

    {   // stage: 16 lanes per row, 8 row-passes; coalesced 256B runs
        int qi = t & 15, r0 = t >> 4;
        #pragma unroll
        for (int p = 0; p < 8; ++p) {
            int r = r0 + 16 * p;
            int sq = qi ^ ((r >> 3) & 7);
            As[r * 16 + sq] = A[(size_t)r * 4096 + k0q + qi];
            Bs[r * 16 + sq] = B[(size_t)r * 4096 + k0q + qi];
        }
    }
    __syncthreads();

    int ty = t >> 4, tx = t & 15;      // thread tile: rows ty*8.., cols tx*8..
    float acc[8][8];
    #pragma unroll
    for (int r = 0; r < 8; ++r)
        #pragma unroll
        for (int c = 0; c < 8; ++c) acc[r][c] = 0.0f;

    for (int qk = 0; qk < 16; ++qk) {  // 16 quads = 64 k-steps
        int sa = qk ^ (ty & 7);
        int sb = qk ^ (tx & 7);
        float4 a4[8], b4[8];
        #pragma unroll
        for (int r = 0; r < 8; ++r) a4[r] = As[(ty * 8 + r) * 16 + sa];
        #pragma unroll
        for (int c = 0; c < 8; ++c) b4[c] = Bs[(tx * 8 + c) * 16 + sb];
        #pragma unroll
        for (int r = 0; r < 8; ++r)
            #pragma unroll
            for (int c = 0; c < 8; ++c) {
                float4 a = a4[r], b = b4[c];
                acc[r][c] = fmaf(a.x, b.x, fmaf(a.y, b.y,
                            fmaf(a.z, b.z, fmaf(a.w, b.w, acc[r][c]))));
            }
    }

    float4* Gq = (float4*)(ws + WS_GP + (size_t)ks * 16384);
    #pragma unroll
    for (int r = 0; r < 8; ++r)
        #pragma unroll
        for (int cc = 0; cc < 2; ++cc)
            Gq[(ty * 8 + r) * 32 + tx * 2 + cc] =
                make_float4(acc[r][cc * 4 + 0], acc[r][cc * 4 + 1],
                            acc[r][cc * 4 + 2], acc[r][cc * 4 + 3]);
}

// ---------------- Register/shuffle 128-pt complex FFT (DIF, bit-reversed out) --
__device__ __forceinline__ void fft128_reg(float& s0r, float& s0i,
                                           float& s1r, float& s1i,
                                           float cA, float sA,
                                           const float* wr, const float* wi,
                                           int lane) {
    float er = s0r + s1r, ei = s0i + s1i;
    float dr = s0r - s1r, di = s0i - s1i;
    float orr = dr * cA - di * sA;
    float oii = dr * sA + di * cA;
    #pragma unroll
    for (int st = 0; st < 6; ++st) {
        int m = 32 >> st;
        bool up = (lane & m) == 0;
        float tr = __shfl_xor(er, m), ti = __shfl_xor(ei, m);
        float ar = tr - er, ai = ti - ei;
        float e2r = up ? (er + tr) : (ar * wr[st] - ai * wi[st]);
        float e2i = up ? (ei + ti) : (ar * wi[st] + ai * wr[st]);
        tr = __shfl_xor(orr, m); ti = __shfl_xor(oii, m);
        float br_ = tr - orr, bi_ = ti - oii;
        float o2r = up ? (orr + tr) : (br_ * wr[st] - bi_ * wi[st]);
        float o2i = up ? (oii + ti) : (br_ * wi[st] + bi_ * wr[st]);
        er = e2r; ei = e2i; orr = o2r; oii = o2i;
    }
    s0r = er; s0i = ei; s1r = orr; s1i = oii;
}

// ---------------- Kernel 2: per-image real 2D FFT + PSD + norm partials --------
// 1024 threads; Z[64][128] in LDS = 64 KB; NO atomics: PSD -> private P slab,
// norms -> 16 per-wave partials.
__global__ __launch_bounds__(1024) void ocl_fft_psd(const float* __restrict__ x1,
                                                    const float* __restrict__ x2,
                                                    float* __restrict__ ws) {
    __shared__ float zre[64 * 128];
    __shared__ float zim[64 * 128];
    int t = threadIdx.x, lane = t & 63, wave = t >> 6;
    int img = blockIdx.x;
    float* P = ws + WS_P + (size_t)img * 8320;
    const float* src = (img < 128) ? (x1 + (size_t)img * 16384)
                                   : (x2 + (size_t)(img - 128) * 16384);

    float cA, sA, wr[6], wi[6];
    {
        float th = -PI_F * (float)lane / 64.0f;
        sincosf(th, &sA, &cA);
        #pragma unroll
        for (int st = 0; st < 6; ++st) {
            int m = 32 >> st;
            float a = -PI_F * (float)(lane & (m - 1)) / (float)m;
            sincosf(a, &wi[st], &wr[st]);
        }
    }
    int rb = (int)(__brev((unsigned)lane) >> 26);  // br6(lane)

    // ---- Row phase: 64 packed row-pair FFTs, 4 per wave; fused ||x||^2 ----
    float nrm = 0.0f;
    #pragma unroll
    for (int pi = 0; pi < 4; ++pi) {
        int p = wave * 4 + pi;
        const float* r0 = src + p * 256 + lane;
        float s0r = r0[0],   s1r = r0[64];
        float s0i = r0[128], s1i = r0[192];
        nrm += s0r * s0r + s1r * s1r + s0i * s0i + s1i * s1i;
        fft128_reg(s0r, s0i, s1r, s1i, cA, sA, wr, wi, lane);
        int f0 = (2 * rb + p) & 127;
        int f1 = (2 * rb + 1 + p) & 127;
        zre[p * 128 + f0] = s0r; zim[p * 128 + f0] = s0i;
        zre[p * 128 + f1] = s1r; zim[p * 128 + f1] = s1i;
    }
    for (int off = 32; off >= 1; off >>= 1) nrm += __shfl_xor(nrm, off);
    if (lane == 0) ws[WS_NP + img * 16 + wave] = nrm;
    __syncthreads();

    // ---- Column phase: 65 column FFTs (k=0..64) over 16 waves ----
    int p0 = (lane >> 1), p1 = 32 + (lane >> 1);
    int par = lane & 1;
    for (int k = wave; k < 65; k += 16) {
        float v0r, v0i, v1r, v1i;
        if (k == 0 || k == 64) {
            int c0 = (k + p0) & 127, c1 = (k + p1) & 127;
            float Z0r = zre[p0 * 128 + c0], Z0i = zim[p0 * 128 + c0];
            float Z1r = zre[p1 * 128 + c1], Z1i = zim[p1 * 128 + c1];
            v0r = par ? Z0i : Z0r; v0i = 0.0f;
            v1r = par ? Z1i : Z1r; v1i = 0.0f;
        } else {
            int kn = 128 - k;
            int ck = (k + p0) & 127, cn = (kn + p0) & 127;
            float Zkr = zre[p0 * 128 + ck], Zki = zim[p0 * 128 + ck];
            float Znr = zre[p0 * 128 + cn], Zni = zim[p0 * 128 + cn];
            float e0r = 0.5f * (Zkr + Znr), e0i = 0.5f * (Zki - Zni);
            float q0r = 0.5f * (Zki + Zni), q0i = 0.5f * (Znr - Zkr);
            v0r = par ? q0r : e0r; v0i = par ? q0i : e0i;
            ck = (k + p1) & 127; cn = (kn + p1) & 127;
            Zkr = zre[p1 * 128 + ck]; Zki = zim[p1 * 128 + ck];
            Znr = zre[p1 * 128 + cn]; Zni = zim[p1 * 128 + cn];
            float e1r = 0.5f * (Zkr + Znr), e1i = 0.5f * (Zki - Zni);
            float q1r = 0.5f * (Zki + Zni), q1i = 0.5f * (Znr - Zkr);
            v1r = par ? q1r : e1r; v1i = par ? q1i : e1i;
        }
        fft128_reg(v0r, v0i, v1r, v1i, cA, sA, wr, wi, lane);
        P[k * 128 + lane]      = v0r * v0r + v0i * v0i;
        P[k * 128 + 64 + lane] = v1r * v1r + v1i * v1i;
    }
}

// ---------------- Kernel 3: fused reductions (grid 130) ------------------------
// blocks [0,65): PSD column k -> (PS[k], PL[k])
// blocks [65,129): Gram slab sum -> G[e], e = (bid-65)*256 + t
// block 129: norm partials -> na/nb
__global__ __launch_bounds__(256) void ocl_reduce(float* __restrict__ ws) {
    int bid = blockIdx.x, t = threadIdx.x;
    if (bid < 65) {
        int k = bid;
        const float* P = ws + WS_P;
        int u = t & 127, c = t >> 7;
        float s = 0.0f;
        const float* base = P + (size_t)(c * 128) * 8320 + k * 128 + u;
        #pragma unroll 4
        for (int im = 0; im < 128; ++im) s += base[(size_t)im * 8320];
        __shared__ float sh[256];
        sh[t] = s;
        __syncthreads();
        float sS = 0.0f, sL = 0.0f;
        if (t < 128) {
            float Su = sh[t] + sh[t + 128];
            float w = (k == 0 || k == 64) ? 1.0f : 2.0f;
            sS = w * Su;
            sL = w * logf(Su);
        }
        for (int off = 32; off >= 1; off >>= 1) {
            sS += __shfl_xor(sS, off);
            sL += __shfl_xor(sL, off);
        }
        __shared__ float aS[4], aL[4];
        if ((t & 63) == 0) { aS[t >> 6] = sS; aL[t >> 6] = sL; }
        __syncthreads();
        if (t == 0) {
            ws[WS_PS + k] = aS[0] + aS[1] + aS[2] + aS[3];
            ws[WS_PL + k] = aL[0] + aL[1] + aL[2] + aL[3];
        }
    } else if (bid < 129) {
        int e = (bid - 65) * 256 + t;
        const float* Gp = ws + WS_GP;
        float s = 0.0f;
        #pragma unroll 8
        for (int sl = 0; sl < 256; ++sl) s += Gp[(size_t)sl * 16384 + e];
        ws[WS_G + e] = s;
    } else {
        // 256 threads: thread t = image index, sums 16 per-wave norm partials
        const float* NP = ws + WS_NP + t * 16;
        float s = 0.0f;
        #pragma unroll
        for (int w = 0; w < 16; ++w) s += NP[w];
        ws[WS_N + t] = s;
    }
}

// ---------------- Kernel 4: tail — LSE rows + PSD pairs -> scalar --------------
__global__ __launch_bounds__(1024) void ocl_tail(const float* __restrict__ ws,
                                                 float* __restrict__ out) {
    int t = threadIdx.x, lane = t & 63, wave = t >> 6;
    const float* na = ws + WS_N;
    const float* nb = ws + WS_N + 128;
    const float* G  = ws + WS_G;

    float rowacc = 0.0f;
    #pragma unroll
    for (int ri = 0; ri < 8; ++ri) {
        int i = wave * 8 + ri;
        int j0 = lane, j1 = 64 + lane;
        size_t b = (size_t)i * 128;
        float d0 = sqrtf(fmaxf(na[i] + nb[j0] - 2.0f * G[b + j0], 0.0f));
        float d1 = sqrtf(fmaxf(na[i] + nb[j1] - 2.0f * G[b + j1], 0.0f));
        float mx = fmaxf(d0, d1);
        for (int off = 32; off >= 1; off >>= 1) mx = fmaxf(mx, __shfl_xor(mx, off));
        float sm = expf(d0 - mx) + expf(d1 - mx);
        for (int off = 32; off >= 1; off >>= 1) sm += __shfl_xor(sm, off);
        float dii = (i < 64) ? __shfl(d0, i) : __shfl(d1, i - 64);
        rowacc += mx + logf(sm) - dii;   // identical on all lanes
    }

    float sS = 0.0f, sL = 0.0f;
    if (t < 65) { sS = ws[WS_PS + t]; sL = ws[WS_PL + t]; }
    for (int off = 32; off >= 1; off >>= 1) {
        sS += __shfl_xor(sS, off);
        sL += __shfl_xor(sL, off);
    }
    __shared__ float aS[16], aL[16], aR[16];
    if (lane == 0) { aS[wave] = sS; aL[wave] = sL; aR[wave] = rowacc; }
    __syncthreads();
    if (t == 0) {
        float S_ = 0.0f, L_ = 0.0f, R_ = 0.0f;
        #pragma unroll
        for (int w = 0; w < 16; ++w) { S_ += aS[w]; L_ += aL[w]; R_ += aR[w]; }
        float ce = R_ / 128.0f;
        float r  = L_ / 16384.0f - logf(S_ / 16384.0f);
        out[0] = ce - 0.1f * r;
    }
}

extern "C" void kernel_launch(void* const* d_in, const int* in_sizes, int n_in,
                              void* d_out, int out_size, void* d_ws, size_t ws_size,
                              hipStream_t stream) {
    (void)in_sizes; (void)n_in; (void)out_size; (void)ws_size;
    const float* x1 = (const float*)d_in[0];
    const float* x2 = (const float*)d_in[1];
    float* ws  = (float*)d_ws;
    float* out = (float*)d_out;

    hipLaunchKernelGGL(ocl_gram,    dim3(256), dim3(256),  0, stream, x1, x2, ws);
    hipLaunchKernelGGL(ocl_fft_psd, dim3(256), dim3(1024), 0, stream, x1, x2, ws);
    hipLaunchKernelGGL(ocl_reduce,  dim3(130), dim3(256),  0, stream, ws);
    hipLaunchKernelGGL(ocl_tail,    dim3(1),   dim3(1024), 0, stream, ws, out);
}

// Round 5
// 106.131 us; speedup vs baseline: 1.3368x; 1.1411x over previous
//
#include <hip/hip_runtime.h>
#include <math.h>

// OneClassLoss: BS=128, HW=128. x1,x2: (128,1,128,128) fp32. Output: scalar fp32.
//
// ws layout (floats) — every region fully overwritten each launch (no memset):
//   [0,256)              na[0..128)|nb[0..128)   (ocl_reduce norm branch)
//   [256,16640)          G[i*128+j] final Gram   (ocl_reduce gram branch)
//   [16640,20736)        NP[img*16+wave] norm partials (ocl_fft_psd)
//   [20736,4215040)      Gp[ks][16384] partial Gram slabs (ocl_gram)
//   [4215040,6344960)    P[img][8320] per-image PSD (ocl_fft_psd)
//   [6344960,6345025)    PS[k] = w_k * sum_u S[k,u]          (ocl_reduce)
//   [6345025,6345090)    PL[k] = w_k * sum_u log S[k,u]      (ocl_reduce)

#define WS_N     0
#define WS_G     256
#define WS_NP    16640
#define WS_GP    20736
#define WS_P     4215040
#define WS_PS    6344960
#define WS_PL    6345025

#define PI_F 3.14159265358979323846f

// ---------------- Kernel 1: Gram partials, LDS-staged GEMM, 256 K-splits -------
__global__ __launch_bounds__(256) void ocl_gram(const float* __restrict__ A_,
                                                const float* __restrict__ B_,
                                                float* __restrict__ ws) {
    __shared__ float4 As[128 * 16];
    __shared__ float4 Bs[128 * 16];
    int ks = blockIdx.x;
    int k0q = ks * 16;                 // quad offset of this K-chunk
    int t = threadIdx.x;
    const float4* A = (const float4*)A_;
    const float4* B = (const float4*)B_;

    {   // stage: 16 lanes per row, 8 row-passes; coalesced 256B runs
        int qi = t & 15, r0 = t >> 4;
        #pragma unroll
        for (int p = 0; p < 8; ++p) {
            int r = r0 + 16 * p;
            int sq = qi ^ ((r >> 3) & 7);
            As[r * 16 + sq] = A[(size_t)r * 4096 + k0q + qi];
            Bs[r * 16 + sq] = B[(size_t)r * 4096 + k0q + qi];
        }
    }
    __syncthreads();

    int ty = t >> 4, tx = t & 15;      // thread tile: rows ty*8.., cols tx*8..
    float acc[8][8];
    #pragma unroll
    for (int r = 0; r < 8; ++r)
        #pragma unroll
        for (int c = 0; c < 8; ++c) acc[r][c] = 0.0f;

    for (int qk = 0; qk < 16; ++qk) {  // 16 quads = 64 k-steps
        int sa = qk ^ (ty & 7);
        int sb = qk ^ (tx & 7);
        float4 a4[8], b4[8];
        #pragma unroll
        for (int r = 0; r < 8; ++r) a4[r] = As[(ty * 8 + r) * 16 + sa];
        #pragma unroll
        for (int c = 0; c < 8; ++c) b4[c] = Bs[(tx * 8 + c) * 16 + sb];
        #pragma unroll
        for (int r = 0; r < 8; ++r)
            #pragma unroll
            for (int c = 0; c < 8; ++c) {
                float4 a = a4[r], b = b4[c];
                acc[r][c] = fmaf(a.x, b.x, fmaf(a.y, b.y,
                            fmaf(a.z, b.z, fmaf(a.w, b.w, acc[r][c]))));
            }
    }

    float4* Gq = (float4*)(ws + WS_GP + (size_t)ks * 16384);
    #pragma unroll
    for (int r = 0; r < 8; ++r)
        #pragma unroll
        for (int cc = 0; cc < 2; ++cc)
            Gq[(ty * 8 + r) * 32 + tx * 2 + cc] =
                make_float4(acc[r][cc * 4 + 0], acc[r][cc * 4 + 1],
                            acc[r][cc * 4 + 2], acc[r][cc * 4 + 3]);
}

// ---------------- Register/shuffle 128-pt complex FFT (DIF, bit-reversed out) --
__device__ __forceinline__ void fft128_reg(float& s0r, float& s0i,
                                           float& s1r, float& s1i,
                                           float cA, float sA,
                                           const float* wr, const float* wi,
                                           int lane) {
    float er = s0r + s1r, ei = s0i + s1i;
    float dr = s0r - s1r, di = s0i - s1i;
    float orr = dr * cA - di * sA;
    float oii = dr * sA + di * cA;
    #pragma unroll
    for (int st = 0; st < 6; ++st) {
        int m = 32 >> st;
        bool up = (lane & m) == 0;
        float tr = __shfl_xor(er, m), ti = __shfl_xor(ei, m);
        float ar = tr - er, ai = ti - ei;
        float e2r = up ? (er + tr) : (ar * wr[st] - ai * wi[st]);
        float e2i = up ? (ei + ti) : (ar * wi[st] + ai * wr[st]);
        tr = __shfl_xor(orr, m); ti = __shfl_xor(oii, m);
        float br_ = tr - orr, bi_ = ti - oii;
        float o2r = up ? (orr + tr) : (br_ * wr[st] - bi_ * wi[st]);
        float o2i = up ? (oii + ti) : (br_ * wi[st] + bi_ * wr[st]);
        er = e2r; ei = e2i; orr = o2r; oii = o2i;
    }
    s0r = er; s0i = ei; s1r = orr; s1i = oii;
}

// ---------------- Kernel 2: per-image real 2D FFT + PSD + norm partials --------
__global__ __launch_bounds__(1024) void ocl_fft_psd(const float* __restrict__ x1,
                                                    const float* __restrict__ x2,
                                                    float* __restrict__ ws) {
    __shared__ float zre[64 * 128];
    __shared__ float zim[64 * 128];
    int t = threadIdx.x, lane = t & 63, wave = t >> 6;
    int img = blockIdx.x;
    float* P = ws + WS_P + (size_t)img * 8320;
    const float* src = (img < 128) ? (x1 + (size_t)img * 16384)
                                   : (x2 + (size_t)(img - 128) * 16384);

    // Twiddles via HW v_sin/v_cos (precision ample for 0.1 threshold)
    float cA, sA, wr[6], wi[6];
    {
        float th = -PI_F * (float)lane / 64.0f;
        sA = __sinf(th); cA = __cosf(th);
        #pragma unroll
        for (int st = 0; st < 6; ++st) {
            int m = 32 >> st;
            float a = -PI_F * (float)(lane & (m - 1)) / (float)m;
            wi[st] = __sinf(a); wr[st] = __cosf(a);
        }
    }
    int rb = (int)(__brev((unsigned)lane) >> 26);  // br6(lane)

    // ---- Row phase: 64 packed row-pair FFTs, 4 per wave; fused ||x||^2 ----
    float nrm = 0.0f;
    #pragma unroll
    for (int pi = 0; pi < 4; ++pi) {
        int p = wave * 4 + pi;
        const float* r0 = src + p * 256 + lane;
        float s0r = r0[0],   s1r = r0[64];
        float s0i = r0[128], s1i = r0[192];
        nrm += s0r * s0r + s1r * s1r + s0i * s0i + s1i * s1i;
        fft128_reg(s0r, s0i, s1r, s1i, cA, sA, wr, wi, lane);
        int f0 = (2 * rb + p) & 127;
        int f1 = (2 * rb + 1 + p) & 127;
        zre[p * 128 + f0] = s0r; zim[p * 128 + f0] = s0i;
        zre[p * 128 + f1] = s1r; zim[p * 128 + f1] = s1i;
    }
    for (int off = 32; off >= 1; off >>= 1) nrm += __shfl_xor(nrm, off);
    if (lane == 0) ws[WS_NP + img * 16 + wave] = nrm;
    __syncthreads();

    // ---- Column phase: 65 column FFTs (k=0..64) over 16 waves ----
    int p0 = (lane >> 1), p1 = 32 + (lane >> 1);
    int par = lane & 1;
    for (int k = wave; k < 65; k += 16) {
        float v0r, v0i, v1r, v1i;
        if (k == 0 || k == 64) {
            int c0 = (k + p0) & 127, c1 = (k + p1) & 127;
            float Z0r = zre[p0 * 128 + c0], Z0i = zim[p0 * 128 + c0];
            float Z1r = zre[p1 * 128 + c1], Z1i = zim[p1 * 128 + c1];
            v0r = par ? Z0i : Z0r; v0i = 0.0f;
            v1r = par ? Z1i : Z1r; v1i = 0.0f;
        } else {
            int kn = 128 - k;
            int ck = (k + p0) & 127, cn = (kn + p0) & 127;
            float Zkr = zre[p0 * 128 + ck], Zki = zim[p0 * 128 + ck];
            float Znr = zre[p0 * 128 + cn], Zni = zim[p0 * 128 + cn];
            float e0r = 0.5f * (Zkr + Znr), e0i = 0.5f * (Zki - Zni);
            float q0r = 0.5f * (Zki + Zni), q0i = 0.5f * (Znr - Zkr);
            v0r = par ? q0r : e0r; v0i = par ? q0i : e0i;
            ck = (k + p1) & 127; cn = (kn + p1) & 127;
            Zkr = zre[p1 * 128 + ck]; Zki = zim[p1 * 128 + ck];
            Znr = zre[p1 * 128 + cn]; Zni = zim[p1 * 128 + cn];
            float e1r = 0.5f * (Zkr + Znr), e1i = 0.5f * (Zki - Zni);
            float q1r = 0.5f * (Zki + Zni), q1i = 0.5f * (Znr - Zkr);
            v1r = par ? q1r : e1r; v1i = par ? q1i : e1i;
        }
        fft128_reg(v0r, v0i, v1r, v1i, cA, sA, wr, wi, lane);
        P[k * 128 + lane]      = v0r * v0r + v0i * v0i;
        P[k * 128 + 64 + lane] = v1r * v1r + v1i * v1i;
    }
}

// ---------------- Kernel 3: fused reductions (grid 322), float4-coalesced ------
// blocks [0,256):   Gram partial sum; block g owns floats [g*64,(g+1)*64)
// blocks [256,321): PSD column k=bid-256 -> (PS[k], PL[k])
// block 321:        norm partials -> na/nb
__global__ __launch_bounds__(256) void ocl_reduce(float* __restrict__ ws) {
    int bid = blockIdx.x, t = threadIdx.x;
    __shared__ float4 sh4[256];
    if (bid < 256) {
        int g = bid;
        const float4* Gp4 = (const float4*)(ws + WS_GP);
        int qi = t & 15, sg = t >> 4;          // 16 quads x 16 slab-groups
        float4 acc = make_float4(0.f, 0.f, 0.f, 0.f);
        #pragma unroll 4
        for (int it = 0; it < 16; ++it) {
            int sl = sg * 16 + it;
            float4 v = Gp4[(size_t)sl * 4096 + g * 16 + qi];
            acc.x += v.x; acc.y += v.y; acc.z += v.z; acc.w += v.w;
        }
        sh4[t] = acc;
        __syncthreads();
        if (t < 16) {
            float4 s = sh4[t];
            #pragma unroll
            for (int sg2 = 1; sg2 < 16; ++sg2) {
                float4 v = sh4[sg2 * 16 + t];
                s.x += v.x; s.y += v.y; s.z += v.z; s.w += v.w;
            }
            ((float4*)(ws + WS_G))[g * 16 + t] = s;
        }
    } else if (bid < 321) {
        int k = bid - 256;
        const float4* P4 = (const float4*)(ws + WS_P);
        int u4 = t & 31, ig = t >> 5;          // 32 quads x 8 image-groups
        float4 acc = make_float4(0.f, 0.f, 0.f, 0.f);
        #pragma unroll 4
        for (int it = 0; it < 32; ++it) {
            int im = ig * 32 + it;
            float4 v = P4[(size_t)im * 2080 + k * 32 + u4];
            acc.x += v.x; acc.y += v.y; acc.z += v.z; acc.w += v.w;
        }
        sh4[t] = acc;
        __syncthreads();
        float sS = 0.0f, sL = 0.0f;
        if (t < 32) {
            float4 s = sh4[t];
            #pragma unroll
            for (int ig2 = 1; ig2 < 8; ++ig2) {
                float4 v = sh4[ig2 * 32 + t];
                s.x += v.x; s.y += v.y; s.z += v.z; s.w += v.w;
            }
            float w = (k == 0 || k == 64) ? 1.0f : 2.0f;
            sS = w * (s.x + s.y + s.z + s.w);
            sL = w * (logf(s.x) + logf(s.y) + logf(s.z) + logf(s.w));
        }
        #pragma unroll
        for (int off = 16; off >= 1; off >>= 1) {
            sS += __shfl_xor(sS, off);
            sL += __shfl_xor(sL, off);
        }
        if (t == 0) {
            ws[WS_PS + k] = sS;
            ws[WS_PL + k] = sL;
        }
    } else {
        const float* NP = ws + WS_NP + t * 16;
        float s = 0.0f;
        #pragma unroll
        for (int w = 0; w < 16; ++w) s += NP[w];
        ws[WS_N + t] = s;
    }
}

// ---------------- Kernel 4: tail — LSE rows + PSD pairs -> scalar --------------
__global__ __launch_bounds__(1024) void ocl_tail(const float* __restrict__ ws,
                                                 float* __restrict__ out) {
    int t = threadIdx.x, lane = t & 63, wave = t >> 6;
    const float* na = ws + WS_N;
    const float* nb = ws + WS_N + 128;
    const float* G  = ws + WS_G;

    float rowacc = 0.0f;
    #pragma unroll
    for (int ri = 0; ri < 8; ++ri) {
        int i = wave * 8 + ri;
        int j0 = lane, j1 = 64 + lane;
        size_t b = (size_t)i * 128;
        float d0 = sqrtf(fmaxf(na[i] + nb[j0] - 2.0f * G[b + j0], 0.0f));
        float d1 = sqrtf(fmaxf(na[i] + nb[j1] - 2.0f * G[b + j1], 0.0f));
        float mx = fmaxf(d0, d1);
        for (int off = 32; off >= 1; off >>= 1) mx = fmaxf(mx, __shfl_xor(mx, off));
        float sm = expf(d0 - mx) + expf(d1 - mx);
        for (int off = 32; off >= 1; off >>= 1) sm += __shfl_xor(sm, off);
        float dii = (i < 64) ? __shfl(d0, i) : __shfl(d1, i - 64);
        rowacc += mx + logf(sm) - dii;   // identical on all lanes
    }

    float sS = 0.0f, sL = 0.0f;
    if (t < 65) { sS = ws[WS_PS + t]; sL = ws[WS_PL + t]; }
    for (int off = 32; off >= 1; off >>= 1) {
        sS += __shfl_xor(sS, off);
        sL += __shfl_xor(sL, off);
    }
    __shared__ float aS[16], aL[16], aR[16];
    if (lane == 0) { aS[wave] = sS; aL[wave] = sL; aR[wave] = rowacc; }
    __syncthreads();
    if (t == 0) {
        float S_ = 0.0f, L_ = 0.0f, R_ = 0.0f;
        #pragma unroll
        for (int w = 0; w < 16; ++w) { S_ += aS[w]; L_ += aL[w]; R_ += aR[w]; }
        float ce = R_ / 128.0f;
        float r  = L_ / 16384.0f - logf(S_ / 16384.0f);
        out[0] = ce - 0.1f * r;
    }
}

extern "C" void kernel_launch(void* const* d_in, const int* in_sizes, int n_in,
                              void* d_out, int out_size, void* d_ws, size_t ws_size,
                              hipStream_t stream) {
    (void)in_sizes; (void)n_in; (void)out_size; (void)ws_size;
    const float* x1 = (const float*)d_in[0];
    const float* x2 = (const float*)d_in[1];
    float* ws  = (float*)d_ws;
    float* out = (float*)d_out;

    hipLaunchKernelGGL(ocl_gram,    dim3(256), dim3(256),  0, stream, x1, x2, ws);
    hipLaunchKernelGGL(ocl_fft_psd, dim3(256), dim3(1024), 0, stream, x1, x2, ws);
    hipLaunchKernelGGL(ocl_reduce,  dim3(322), dim3(256),  0, stream, ws);
    hipLaunchKernelGGL(ocl_tail,    dim3(1),   dim3(1024), 0, stream, ws, out);
}